// Round 9
// baseline (41.347 us; speedup 1.0000x reference)
//
#include <hip/hip_runtime.h>

#define N_IN_   1024
#define N_OUT_  1536
#define N_CH    16
#define TY      6       // output rows per block tile (6 | 768: never straddles ifftshift wrap)
#define XT      256     // output cols per block tile (256 | 768)
#define XW      64      // staged input x-window (max span 61 < 64)
#define NBX     (N_OUT_ / XT)          // 6
#define NBY     (N_OUT_ / TY)          // 256
#define NBLK    (NBX * NBY)            // 1536 = 8 * 192 (exact XCD split)

typedef float f4_t __attribute__((ext_vector_type(4)));

// Catmull-Rom-style cubic kernel, matching the reference formula in f32.
// Exact 0 for |x| >= 2 -> widened tap windows are formula-identical.
__device__ __forceinline__ float cubic_w(float x) {
    float ax = fabsf(x);
    float f1 = 1.0f + ax * ax * (1.5f * ax - 2.5f);
    float t  = 2.0f - ax;
    float f2 = -0.5f * (ax - 1.0f) * t * t;
    return ax <= 1.0f ? f1 : (ax < 2.0f ? f2 : 0.0f);
}

__device__ __forceinline__ float u_of_j(int j) {
    const float c0 = -0.5f / 0.05f;                        // k_in[0] = -10
    const float c1 = (-0.5f + 1.0f / 1023.0f) / 0.05f;     // k_in[1]
    const float h  = c1 - c0;
    float kout = (-0.5f + (float)j * (1.0f / 1535.0f)) / 0.15f;
    return (kout - c0) / h;                                // in [341, 682]
}

// One block: output tile [y0..y0+5] x [X0..X0+255] x all 16 channels.
// Wave w stages AND computes channels 4w..4w+3. Thread: 4 ch x 4 cols x 6 rows.
// 1-D grid with XCD-banded swizzle: XCD k owns contiguous y-band [32k, 32k+32),
// all 6 x-tiles of a row on the same XCD -> contiguous 6 KB row writes per L2
// and intra-XCD L2 reuse of overlapping staged input rows.
__global__ __launch_bounds__(256)
void fused_lds(const float* __restrict__ re, float* __restrict__ out) {
    const int tid = threadIdx.x;
    const int wv  = tid >> 6;       // wave 0..3
    const int ln  = tid & 63;       // lane

    // bijective swizzle: gid -> (bx, by) with y-bands per XCD
    const int gid = blockIdx.x;
    const int g2  = (gid & 7) * (NBLK / 8) + (gid >> 3);
    const int bx  = g2 % NBX;
    const int by  = g2 / NBX;

    const int X0  = bx * XT;
    const int y0  = by * TY;
    const int jx0 = X0 < 768 ? X0 + 768 : X0 - 768;   // contiguous over tile
    const int jy0 = y0 < 768 ? y0 + 768 : y0 - 768;

    // x stage window: covers all taps of the 256 output cols
    int stage_b = (int)floorf(u_of_j(jx0)) - 1;
    stage_b = min(max(stage_b, 0), N_IN_ - XW);
    // y input window: 6 rows cover all taps of the 6 output rows
    int byb = (int)floorf(u_of_j(jy0)) - 1;
    byb = min(max(byb, 0), N_IN_ - TY);

    __shared__ float lds[N_CH][TY][XW];

    // y row -> fftshifted memory row offset (block-uniform)
    int rmofs[TY];
    #pragma unroll
    for (int j = 0; j < TY; ++j) {
        int r = byb + j;
        rmofs[j] = ((r >= 512) ? (r - 512) : (r + 512)) * N_IN_;
    }

    // ---- stage: wave-local, 4ch x 6rows x 64cols = 6 KB per wave ----
    const bool hi = (stage_b >= 512);
    const bool lo = (stage_b + XW <= 512);
    if (hi || lo) {
        const int xbase = hi ? (stage_b - 512) : (stage_b + 512);
        #pragma unroll
        for (int k = 0; k < 6; ++k) {
            const int t   = k * 64 + ln;          // 0..383 within wave
            const int ch  = t / 96;               // 0..3 (local)
            const int rem = t - ch * 96;
            const int row = rem >> 4;             // 0..5
            const int q   = rem & 15;             // float4 index in row
            const int c   = 4 * wv + ch;
            f4_t v;
            __builtin_memcpy(&v,
                re + (size_t)c * (N_IN_ * N_IN_) + rmofs[row] + xbase + 4 * q, 16);
            *(f4_t*)&lds[c][row][4 * q] = v;
        }
    } else {
        // straddling window (2 of 6 x-tiles): per-element gather, wave-local
        const int t = stage_b + ln;
        const int cmem = (t >= 512) ? (t - 512) : (t + 512);
        #pragma unroll
        for (int s = 0; s < 4 * TY; ++s) {
            const int ch  = s / TY;               // 0..3 (local)
            const int row = s - ch * TY;
            const int c   = 4 * wv + ch;
            lds[c][row][ln] =
                re[(size_t)c * (N_IN_ * N_IN_) + rmofs[row] + cmem];
        }
    }

    // ---- weights (overlap staging latency) ----
    // y 6x6 matrix, block-uniform; RES_RATIO=3 folded here.
    float wmat[TY][TY];
    #pragma unroll
    for (int i = 0; i < TY; ++i) {
        float ui = u_of_j(jy0 + i);
        #pragma unroll
        for (int j = 0; j < TY; ++j)
            wmat[i][j] = 3.0f * cubic_w(ui - (float)(byb + j));
    }

    // per-thread: 4 consecutive output cols, one shared 6-wide x window
    const int x0l = ln * 4;
    float wx6[4][6];
    int w0;
    {
        float u0 = u_of_j(jx0 + x0l);
        w0 = (int)floorf(u0) - 1 - stage_b;       // 0..57
        w0 = min(max(w0, 0), XW - 6);
        #pragma unroll
        for (int k = 0; k < 4; ++k) {
            float uk = u_of_j(jx0 + x0l + k);
            #pragma unroll
            for (int j = 0; j < 6; ++j)
                wx6[k][j] = cubic_w(uk - (float)(stage_b + w0 + j));
        }
    }

    __syncthreads();

    #pragma unroll
    for (int cc = 0; cc < 4; ++cc) {
        const int c = 4 * wv + cc;
        float acc[TY][4];
        #pragma unroll
        for (int i = 0; i < TY; ++i)
            #pragma unroll
            for (int k = 0; k < 4; ++k) acc[i][k] = 0.0f;

        #pragma unroll
        for (int j = 0; j < TY; ++j) {
            const float* p = &lds[c][j][w0];
            const float L0 = p[0], L1 = p[1], L2 = p[2],
                        L3 = p[3], L4 = p[4], L5 = p[5];
            float xr0, xr1, xr2, xr3;
            xr0 = fmaf(wx6[0][5], L5, fmaf(wx6[0][4], L4, fmaf(wx6[0][3], L3,
                  fmaf(wx6[0][2], L2, fmaf(wx6[0][1], L1, wx6[0][0] * L0)))));
            xr1 = fmaf(wx6[1][5], L5, fmaf(wx6[1][4], L4, fmaf(wx6[1][3], L3,
                  fmaf(wx6[1][2], L2, fmaf(wx6[1][1], L1, wx6[1][0] * L0)))));
            xr2 = fmaf(wx6[2][5], L5, fmaf(wx6[2][4], L4, fmaf(wx6[2][3], L3,
                  fmaf(wx6[2][2], L2, fmaf(wx6[2][1], L1, wx6[2][0] * L0)))));
            xr3 = fmaf(wx6[3][5], L5, fmaf(wx6[3][4], L4, fmaf(wx6[3][3], L3,
                  fmaf(wx6[3][2], L2, fmaf(wx6[3][1], L1, wx6[3][0] * L0)))));
            #pragma unroll
            for (int i = 0; i < TY; ++i) {
                const float w = wmat[i][j];
                acc[i][0] = fmaf(w, xr0, acc[i][0]);
                acc[i][1] = fmaf(w, xr1, acc[i][1]);
                acc[i][2] = fmaf(w, xr2, acc[i][2]);
                acc[i][3] = fmaf(w, xr3, acc[i][3]);
            }
        }

        float* ob = out + (size_t)c * (N_OUT_ * N_OUT_)
                        + (size_t)y0 * N_OUT_ + X0 + x0l;
        #pragma unroll
        for (int i = 0; i < TY; ++i) {
            f4_t a = { acc[i][0], acc[i][1], acc[i][2], acc[i][3] };
            __builtin_nontemporal_store(a, (f4_t*)(ob + (size_t)i * N_OUT_));
        }
    }
}

// ---------------- Defensive: complex-interleaved output variant --------------
__global__ __launch_bounds__(256)
void resample_cplx(const float* __restrict__ re,
                   const float* __restrict__ im,
                   float2* __restrict__ out) {
    const int x = blockIdx.x * 256 + threadIdx.x;
    const int y = blockIdx.y;
    const int jx = x < 768 ? x + 768 : x - 768;
    const int jy = y < 768 ? y + 768 : y - 768;

    float ux = u_of_j(jx), uy = u_of_j(jy);
    int bx = min(max((int)floorf(ux) - 1, 0), N_IN_ - 4);
    int by = min(max((int)floorf(uy) - 1, 0), N_IN_ - 4);
    float wx[4], wy[4];
    #pragma unroll
    for (int d = 0; d < 4; ++d) {
        wx[d] = cubic_w(ux - (float)(bx + d));
        wy[d] = 3.0f * cubic_w(uy - (float)(by + d));
    }
    float w[4][4];
    #pragma unroll
    for (int dy = 0; dy < 4; ++dy)
        #pragma unroll
        for (int dx = 0; dx < 4; ++dx) w[dy][dx] = wy[dy] * wx[dx];

    int rofs[4];
    #pragma unroll
    for (int dy = 0; dy < 4; ++dy) {
        int t = by + dy;
        rofs[dy] = ((t >= 512) ? (t - 512) : (t + 512)) * N_IN_;
    }
    int cm[4];
    #pragma unroll
    for (int d = 0; d < 4; ++d) {
        int t = bx + d;
        cm[d] = (t >= 512) ? (t - 512) : (t + 512);
    }

    const int outbase = y * N_OUT_ + x;
    for (int c = 0; c < N_CH; ++c) {
        const float* rec = re + (size_t)c * (N_IN_ * N_IN_);
        const float* imc = im + (size_t)c * (N_IN_ * N_IN_);
        float ar = 0.0f, ai = 0.0f;
        #pragma unroll
        for (int dy = 0; dy < 4; ++dy) {
            #pragma unroll
            for (int d = 0; d < 4; ++d) {
                ar = fmaf(w[dy][d], rec[rofs[dy] + cm[d]], ar);
                ai = fmaf(w[dy][d], imc[rofs[dy] + cm[d]], ai);
            }
        }
        out[(size_t)c * (N_OUT_ * N_OUT_) + outbase] = make_float2(ar, ai);
    }
}

extern "C" void kernel_launch(void* const* d_in, const int* in_sizes, int n_in,
                              void* d_out, int out_size, void* d_ws, size_t ws_size,
                              hipStream_t stream) {
    const float* re = (const float*)d_in[0];   // kimage_real (16,1024,1024)
    const float* im = (const float*)d_in[1];   // kimage_imag (16,1024,1024)

    if (out_size >= 2 * N_CH * N_OUT_ * N_OUT_) {
        // complex-interleaved output (defensive; not the observed case)
        resample_cplx<<<dim3(N_OUT_ / 256, N_OUT_), dim3(256), 0, stream>>>(
            re, im, (float2*)d_out);
    } else {
        fused_lds<<<dim3(NBLK), dim3(256), 0, stream>>>(re, (float*)d_out);
    }
}

// Round 10
// 40.357 us; speedup vs baseline: 1.0245x; 1.0245x over previous
//
#include <hip/hip_runtime.h>

#define N_IN_   1024
#define N_OUT_  1536
#define N_CH    16
#define TY      6        // output rows per block (6 | 768: tile never straddles ifftshift wrap)
#define CPB     4        // channels per block
#define IDX0    340      // first input index ever touched (u in [341,682])
#define XWF     348      // staged row width: 346 valid + 2 pad (f4 multiple)
#define SEGA    172      // idx [340,512) -> mem 852+e ; idx [512,686) -> mem e-172
#define NTHR    384      // 6 waves; 384 * 4 cols = 1536
#define STAGE_Q 87       // float4 quads per (ch,row): 43 (segA) + 44 (segB)
#define STAGE_T (CPB * TY * STAGE_Q)   // 2088 stage tasks

typedef float f4_t __attribute__((ext_vector_type(4)));

// Catmull-Rom-style cubic kernel, matching the reference formula in f32.
// Exact 0 for |x| >= 2 -> widened tap windows are formula-identical.
__device__ __forceinline__ float cubic_w(float x) {
    float ax = fabsf(x);
    float f1 = 1.0f + ax * ax * (1.5f * ax - 2.5f);
    float t  = 2.0f - ax;
    float f2 = -0.5f * (ax - 1.0f) * t * t;
    return ax <= 1.0f ? f1 : (ax < 2.0f ? f2 : 0.0f);
}

__device__ __forceinline__ float u_of_j(int j) {
    const float c0 = -0.5f / 0.05f;                        // k_in[0] = -10
    const float c1 = (-0.5f + 1.0f / 1023.0f) / 0.05f;     // k_in[1]
    const float h  = c1 - c0;
    float kout = (-0.5f + (float)j * (1.0f / 1535.0f)) / 0.15f;
    return (kout - c0) / h;                                // in [341, 682]
}

// One block: 4 channels x 6 output rows x ALL 1536 cols.
// Writes 4 contiguous 36 KB slabs (rows y0..y0+5 adjacent in memory) ->
// deterministic DRAM page locality, independent of dispatch co-timing.
__global__ __launch_bounds__(NTHR)
void fused_row(const float* __restrict__ re, float* __restrict__ out) {
    const int tid = threadIdx.x;
    const int gy  = blockIdx.x & 255;          // y-tile (fastest -> neighbors co-timed)
    const int gc  = blockIdx.x >> 8;           // channel group
    const int c0  = gc * CPB;
    const int y0  = gy * TY;
    const int jy0 = y0 < 768 ? y0 + 768 : y0 - 768;

    // y input window: 6 rows cover all taps of the 6 output rows
    int byb = (int)floorf(u_of_j(jy0)) - 1;    // in [340, 680]
    byb = min(max(byb, 0), N_IN_ - TY);
    int rm[TY];                                 // fftshifted memory row offsets
    #pragma unroll
    for (int j = 0; j < TY; ++j) {
        int r = byb + j;
        rm[j] = ((r >= 512) ? (r - 512) : (r + 512)) * N_IN_;
    }

    __shared__ float lds[CPB][TY][XWF];
    __shared__ float wmT[TY][8];               // wmT[j][i]: y-weight, tap j, output i

    // ---- stage: fixed x-window idx [340,686) = two linear memory segments ----
    // e in [0,172): mem col 852+e ; e in [172,348): mem col e-172. All f4-aligned.
    #pragma unroll
    for (int k = 0; k < 6; ++k) {
        const int t = k * NTHR + tid;
        if (t < STAGE_T) {
            const int pr  = t / STAGE_Q;       // (ch,row) 0..23
            const int q   = t - pr * STAGE_Q;  // quad 0..86
            const int ch  = pr / TY;
            const int row = pr - ch * TY;
            int so, eo;
            if (q < 43) { so = 852 + 4 * q; eo = 4 * q; }
            else        { int q2 = q - 43; so = 4 * q2; eo = SEGA + 4 * q2; }
            f4_t v;
            __builtin_memcpy(&v,
                re + (size_t)(c0 + ch) * (N_IN_ * N_IN_) + rm[row] + so, 16);
            *(f4_t*)&lds[ch][row][eo] = v;
        }
    }

    // ---- y weights: cooperative (block-uniform), RES_RATIO=3 folded ----
    if (tid < TY * TY) {
        const int j = tid / TY, i = tid - TY * j;
        wmT[j][i] = 3.0f * cubic_w(u_of_j(jy0 + i) - (float)(byb + j));
    }

    // ---- x weights: per-thread quad of 4 cols, one shared 6-wide window ----
    const int col0 = 4 * tid;                  // quad never straddles 768 (4 | 768)
    const int jx0  = col0 < 768 ? col0 + 768 : col0 - 768;
    int w0 = (int)floorf(u_of_j(jx0)) - 1 - IDX0;   // 0..341
    w0 = min(max(w0, 0), XWF - 6);
    float wx6[4][6];
    #pragma unroll
    for (int k = 0; k < 4; ++k) {
        float uk = u_of_j(jx0 + k);
        #pragma unroll
        for (int j = 0; j < 6; ++j)
            wx6[k][j] = cubic_w(uk - (float)(IDX0 + w0 + j));
    }

    __syncthreads();

    #pragma unroll
    for (int cc = 0; cc < CPB; ++cc) {
        float acc[TY][4];
        #pragma unroll
        for (int i = 0; i < TY; ++i)
            #pragma unroll
            for (int k = 0; k < 4; ++k) acc[i][k] = 0.0f;

        #pragma unroll
        for (int j = 0; j < TY; ++j) {
            const float* p = &lds[cc][j][w0];
            const float L0 = p[0], L1 = p[1], L2 = p[2],
                        L3 = p[3], L4 = p[4], L5 = p[5];
            float xr0, xr1, xr2, xr3;
            xr0 = fmaf(wx6[0][5], L5, fmaf(wx6[0][4], L4, fmaf(wx6[0][3], L3,
                  fmaf(wx6[0][2], L2, fmaf(wx6[0][1], L1, wx6[0][0] * L0)))));
            xr1 = fmaf(wx6[1][5], L5, fmaf(wx6[1][4], L4, fmaf(wx6[1][3], L3,
                  fmaf(wx6[1][2], L2, fmaf(wx6[1][1], L1, wx6[1][0] * L0)))));
            xr2 = fmaf(wx6[2][5], L5, fmaf(wx6[2][4], L4, fmaf(wx6[2][3], L3,
                  fmaf(wx6[2][2], L2, fmaf(wx6[2][1], L1, wx6[2][0] * L0)))));
            xr3 = fmaf(wx6[3][5], L5, fmaf(wx6[3][4], L4, fmaf(wx6[3][3], L3,
                  fmaf(wx6[3][2], L2, fmaf(wx6[3][1], L1, wx6[3][0] * L0)))));

            const f4_t wlo = *(const f4_t*)&wmT[j][0];  // outputs 0..3
            const float w4 = wmT[j][4], w5 = wmT[j][5];
            acc[0][0] = fmaf(wlo.x, xr0, acc[0][0]);
            acc[0][1] = fmaf(wlo.x, xr1, acc[0][1]);
            acc[0][2] = fmaf(wlo.x, xr2, acc[0][2]);
            acc[0][3] = fmaf(wlo.x, xr3, acc[0][3]);
            acc[1][0] = fmaf(wlo.y, xr0, acc[1][0]);
            acc[1][1] = fmaf(wlo.y, xr1, acc[1][1]);
            acc[1][2] = fmaf(wlo.y, xr2, acc[1][2]);
            acc[1][3] = fmaf(wlo.y, xr3, acc[1][3]);
            acc[2][0] = fmaf(wlo.z, xr0, acc[2][0]);
            acc[2][1] = fmaf(wlo.z, xr1, acc[2][1]);
            acc[2][2] = fmaf(wlo.z, xr2, acc[2][2]);
            acc[2][3] = fmaf(wlo.z, xr3, acc[2][3]);
            acc[3][0] = fmaf(wlo.w, xr0, acc[3][0]);
            acc[3][1] = fmaf(wlo.w, xr1, acc[3][1]);
            acc[3][2] = fmaf(wlo.w, xr2, acc[3][2]);
            acc[3][3] = fmaf(wlo.w, xr3, acc[3][3]);
            acc[4][0] = fmaf(w4, xr0, acc[4][0]);
            acc[4][1] = fmaf(w4, xr1, acc[4][1]);
            acc[4][2] = fmaf(w4, xr2, acc[4][2]);
            acc[4][3] = fmaf(w4, xr3, acc[4][3]);
            acc[5][0] = fmaf(w5, xr0, acc[5][0]);
            acc[5][1] = fmaf(w5, xr1, acc[5][1]);
            acc[5][2] = fmaf(w5, xr2, acc[5][2]);
            acc[5][3] = fmaf(w5, xr3, acc[5][3]);
        }

        float* ob = out + (size_t)(c0 + cc) * (N_OUT_ * N_OUT_)
                        + (size_t)y0 * N_OUT_ + col0;
        #pragma unroll
        for (int i = 0; i < TY; ++i) {
            f4_t a = { acc[i][0], acc[i][1], acc[i][2], acc[i][3] };
            __builtin_nontemporal_store(a, (f4_t*)(ob + (size_t)i * N_OUT_));
        }
    }
}

// ---------------- Defensive: complex-interleaved output variant --------------
__global__ __launch_bounds__(256)
void resample_cplx(const float* __restrict__ re,
                   const float* __restrict__ im,
                   float2* __restrict__ out) {
    const int x = blockIdx.x * 256 + threadIdx.x;
    const int y = blockIdx.y;
    const int jx = x < 768 ? x + 768 : x - 768;
    const int jy = y < 768 ? y + 768 : y - 768;

    float ux = u_of_j(jx), uy = u_of_j(jy);
    int bx = min(max((int)floorf(ux) - 1, 0), N_IN_ - 4);
    int by = min(max((int)floorf(uy) - 1, 0), N_IN_ - 4);
    float wx[4], wy[4];
    #pragma unroll
    for (int d = 0; d < 4; ++d) {
        wx[d] = cubic_w(ux - (float)(bx + d));
        wy[d] = 3.0f * cubic_w(uy - (float)(by + d));
    }
    float w[4][4];
    #pragma unroll
    for (int dy = 0; dy < 4; ++dy)
        #pragma unroll
        for (int dx = 0; dx < 4; ++dx) w[dy][dx] = wy[dy] * wx[dx];

    int rofs[4];
    #pragma unroll
    for (int dy = 0; dy < 4; ++dy) {
        int t = by + dy;
        rofs[dy] = ((t >= 512) ? (t - 512) : (t + 512)) * N_IN_;
    }
    int cm[4];
    #pragma unroll
    for (int d = 0; d < 4; ++d) {
        int t = bx + d;
        cm[d] = (t >= 512) ? (t - 512) : (t + 512);
    }

    const int outbase = y * N_OUT_ + x;
    for (int c = 0; c < N_CH; ++c) {
        const float* rec = re + (size_t)c * (N_IN_ * N_IN_);
        const float* imc = im + (size_t)c * (N_IN_ * N_IN_);
        float ar = 0.0f, ai = 0.0f;
        #pragma unroll
        for (int dy = 0; dy < 4; ++dy) {
            #pragma unroll
            for (int d = 0; d < 4; ++d) {
                ar = fmaf(w[dy][d], rec[rofs[dy] + cm[d]], ar);
                ai = fmaf(w[dy][d], imc[rofs[dy] + cm[d]], ai);
            }
        }
        out[(size_t)c * (N_OUT_ * N_OUT_) + outbase] = make_float2(ar, ai);
    }
}

extern "C" void kernel_launch(void* const* d_in, const int* in_sizes, int n_in,
                              void* d_out, int out_size, void* d_ws, size_t ws_size,
                              hipStream_t stream) {
    const float* re = (const float*)d_in[0];   // kimage_real (16,1024,1024)
    const float* im = (const float*)d_in[1];   // kimage_imag (16,1024,1024)

    if (out_size >= 2 * N_CH * N_OUT_ * N_OUT_) {
        // complex-interleaved output (defensive; not the observed case)
        resample_cplx<<<dim3(N_OUT_ / 256, N_OUT_), dim3(256), 0, stream>>>(
            re, im, (float2*)d_out);
    } else {
        fused_row<<<dim3(256 * (N_CH / CPB)), dim3(NTHR), 0, stream>>>(
            re, (float*)d_out);
    }
}

// Round 11
// 37.023 us; speedup vs baseline: 1.1168x; 1.0901x over previous
//
#include <hip/hip_runtime.h>

#define N_IN_   1024
#define N_OUT_  1536
#define N_CH    16
#define TY      6       // output rows per block tile (6 | 768)
#define XT      256     // output cols per block tile
#define XW      64      // staged input x-window (max span 61 < 64)

typedef float f4_t __attribute__((ext_vector_type(4)));

// Catmull-Rom-style cubic kernel, matching the reference formula in f32.
// Exact 0 for |x| >= 2 -> widened tap windows are formula-identical.
__device__ __forceinline__ float cubic_w(float x) {
    float ax = fabsf(x);
    float f1 = 1.0f + ax * ax * (1.5f * ax - 2.5f);
    float t  = 2.0f - ax;
    float f2 = -0.5f * (ax - 1.0f) * t * t;
    return ax <= 1.0f ? f1 : (ax < 2.0f ? f2 : 0.0f);
}

__device__ __forceinline__ float u_of_j(int j) {
    const float c0 = -0.5f / 0.05f;                        // k_in[0] = -10
    const float c1 = (-0.5f + 1.0f / 1023.0f) / 0.05f;     // k_in[1]
    const float h  = c1 - c0;
    float kout = (-0.5f + (float)j * (1.0f / 1535.0f)) / 0.15f;
    return (kout - c0) / h;                                // in [341, 682]
}

// One block: output tile [y0..y0+5] x [X0..X0+255] x all 16 channels.
// Wave w owns channels 4w..4w+3 end-to-end (stage AND compute) -> NO block
// barrier needed. Channels processed as 2 pairs, software-pipelined: both
// pairs' global loads issued up front; ds_write of pair0 gets a counted
// vmcnt (pair1 stays in flight under pair0's compute+stores).
__global__ __launch_bounds__(256)
void fused_pipe(const float* __restrict__ re, float* __restrict__ out) {
    const int tid = threadIdx.x;
    const int wv  = tid >> 6;       // wave 0..3
    const int ln  = tid & 63;       // lane
    const int X0  = blockIdx.x * XT;
    const int y0  = blockIdx.y * TY;
    const int jx0 = X0 < 768 ? X0 + 768 : X0 - 768;   // contiguous over tile
    const int jy0 = y0 < 768 ? y0 + 768 : y0 - 768;

    int stage_b = (int)floorf(u_of_j(jx0)) - 1;
    stage_b = min(max(stage_b, 0), N_IN_ - XW);
    int byb = (int)floorf(u_of_j(jy0)) - 1;
    byb = min(max(byb, 0), N_IN_ - TY);

    __shared__ __align__(16) float lds[4][2][TY][XW];   // [wave][ch-in-pair][row][col] 12 KB
    __shared__ __align__(16) float wlds[4][TY][8];      // per-wave y-weight matrix copy

    const bool hi = (stage_b >= 512);
    const bool lo = (stage_b + XW <= 512);
    const bool contig = hi || lo;                       // block-uniform branch
    const int xbase = hi ? (stage_b - 512) : (stage_b + 512);

    // per-thread x weights (computed under stage-load latency)
    const int col0 = 4 * ln;
    const int jxc  = jx0 + col0;
    int w0;
    float wx6[4][6];

// wmat (wave-local copy in LDS; RES_RATIO=3 folded) + wx6 setup
#define SETUP_W() do {                                                        \
    if (ln < 36) {                                                            \
        const int j_ = ln / 6, i_ = ln - 6 * j_;                              \
        wlds[wv][j_][i_] = 3.0f * cubic_w(u_of_j(jy0 + i_) - (float)(byb + j_)); \
    }                                                                         \
    w0 = (int)floorf(u_of_j(jxc)) - 1 - stage_b;                              \
    w0 = min(max(w0, 0), XW - 6);                                             \
    _Pragma("unroll")                                                         \
    for (int k = 0; k < 4; ++k) {                                             \
        float uk = u_of_j(jxc + k);                                           \
        _Pragma("unroll")                                                     \
        for (int j = 0; j < 6; ++j)                                           \
            wx6[k][j] = cubic_w(uk - (float)(stage_b + w0 + j));              \
    }                                                                         \
} while (0)

// compute + store one channel from lds[wv][PL] (PL static)
#define COMPUTE_ONE(PL, CCH) do {                                             \
    float acc[TY][4];                                                         \
    _Pragma("unroll")                                                         \
    for (int i = 0; i < TY; ++i) {                                            \
        acc[i][0] = 0.f; acc[i][1] = 0.f; acc[i][2] = 0.f; acc[i][3] = 0.f;   \
    }                                                                         \
    _Pragma("unroll")                                                         \
    for (int j = 0; j < TY; ++j) {                                            \
        const float* p = &lds[wv][PL][j][w0];                                 \
        const float L0 = p[0], L1 = p[1], L2 = p[2],                          \
                    L3 = p[3], L4 = p[4], L5 = p[5];                          \
        float xr0, xr1, xr2, xr3;                                             \
        xr0 = fmaf(wx6[0][5], L5, fmaf(wx6[0][4], L4, fmaf(wx6[0][3], L3,     \
              fmaf(wx6[0][2], L2, fmaf(wx6[0][1], L1, wx6[0][0] * L0)))));    \
        xr1 = fmaf(wx6[1][5], L5, fmaf(wx6[1][4], L4, fmaf(wx6[1][3], L3,     \
              fmaf(wx6[1][2], L2, fmaf(wx6[1][1], L1, wx6[1][0] * L0)))));    \
        xr2 = fmaf(wx6[2][5], L5, fmaf(wx6[2][4], L4, fmaf(wx6[2][3], L3,     \
              fmaf(wx6[2][2], L2, fmaf(wx6[2][1], L1, wx6[2][0] * L0)))));    \
        xr3 = fmaf(wx6[3][5], L5, fmaf(wx6[3][4], L4, fmaf(wx6[3][3], L3,     \
              fmaf(wx6[3][2], L2, fmaf(wx6[3][1], L1, wx6[3][0] * L0)))));    \
        const f4_t wlo = *(const f4_t*)&wlds[wv][j][0];                       \
        const float w4 = wlds[wv][j][4], w5 = wlds[wv][j][5];                 \
        acc[0][0] = fmaf(wlo.x, xr0, acc[0][0]);                              \
        acc[0][1] = fmaf(wlo.x, xr1, acc[0][1]);                              \
        acc[0][2] = fmaf(wlo.x, xr2, acc[0][2]);                              \
        acc[0][3] = fmaf(wlo.x, xr3, acc[0][3]);                              \
        acc[1][0] = fmaf(wlo.y, xr0, acc[1][0]);                              \
        acc[1][1] = fmaf(wlo.y, xr1, acc[1][1]);                              \
        acc[1][2] = fmaf(wlo.y, xr2, acc[1][2]);                              \
        acc[1][3] = fmaf(wlo.y, xr3, acc[1][3]);                              \
        acc[2][0] = fmaf(wlo.z, xr0, acc[2][0]);                              \
        acc[2][1] = fmaf(wlo.z, xr1, acc[2][1]);                              \
        acc[2][2] = fmaf(wlo.z, xr2, acc[2][2]);                              \
        acc[2][3] = fmaf(wlo.z, xr3, acc[2][3]);                              \
        acc[3][0] = fmaf(wlo.w, xr0, acc[3][0]);                              \
        acc[3][1] = fmaf(wlo.w, xr1, acc[3][1]);                              \
        acc[3][2] = fmaf(wlo.w, xr2, acc[3][2]);                              \
        acc[3][3] = fmaf(wlo.w, xr3, acc[3][3]);                              \
        acc[4][0] = fmaf(w4, xr0, acc[4][0]);                                 \
        acc[4][1] = fmaf(w4, xr1, acc[4][1]);                                 \
        acc[4][2] = fmaf(w4, xr2, acc[4][2]);                                 \
        acc[4][3] = fmaf(w4, xr3, acc[4][3]);                                 \
        acc[5][0] = fmaf(w5, xr0, acc[5][0]);                                 \
        acc[5][1] = fmaf(w5, xr1, acc[5][1]);                                 \
        acc[5][2] = fmaf(w5, xr2, acc[5][2]);                                 \
        acc[5][3] = fmaf(w5, xr3, acc[5][3]);                                 \
    }                                                                         \
    float* ob = out + (size_t)(CCH) * (N_OUT_ * N_OUT_)                       \
                    + (size_t)y0 * N_OUT_ + X0 + col0;                        \
    _Pragma("unroll")                                                         \
    for (int i = 0; i < TY; ++i) {                                            \
        f4_t a = { acc[i][0], acc[i][1], acc[i][2], acc[i][3] };              \
        __builtin_nontemporal_store(a, (f4_t*)(ob + (size_t)i * N_OUT_));     \
    }                                                                         \
} while (0)

#define WAVE_FENCE() do {                                                     \
    asm volatile("s_waitcnt lgkmcnt(0)" ::: "memory");                        \
    __builtin_amdgcn_sched_barrier(0);                                        \
} while (0)

    if (contig) {
        // f4 task decode: t=k*64+ln; ch=t/96; row=(t-96ch)>>4; q=t&15
        f4_t ra[3], rb[3];
        #pragma unroll
        for (int k = 0; k < 3; ++k) {
            const int t = k * 64 + ln;
            const int ch = t / 96, rem = t - ch * 96, row = rem >> 4, q = rem & 15;
            const int rr = byb + row;
            const int rmem = (rr >= 512) ? rr - 512 : rr + 512;
            __builtin_memcpy(&ra[k], re + (size_t)(4 * wv + ch) * (N_IN_ * N_IN_)
                                        + (size_t)rmem * N_IN_ + xbase + 4 * q, 16);
        }
        #pragma unroll
        for (int k = 0; k < 3; ++k) {
            const int t = k * 64 + ln;
            const int ch = t / 96, rem = t - ch * 96, row = rem >> 4, q = rem & 15;
            const int rr = byb + row;
            const int rmem = (rr >= 512) ? rr - 512 : rr + 512;
            __builtin_memcpy(&rb[k], re + (size_t)(4 * wv + 2 + ch) * (N_IN_ * N_IN_)
                                        + (size_t)rmem * N_IN_ + xbase + 4 * q, 16);
        }
        SETUP_W();
        __builtin_amdgcn_sched_barrier(0);
        // pair 0: ds_write waits only pair0's loads (counted vmcnt; rb in flight)
        #pragma unroll
        for (int k = 0; k < 3; ++k) {
            const int t = k * 64 + ln;
            const int ch = t / 96, rem = t - ch * 96, row = rem >> 4, q = rem & 15;
            *(f4_t*)&lds[wv][ch][row][4 * q] = ra[k];
        }
        WAVE_FENCE();
        COMPUTE_ONE(0, 4 * wv + 0);
        COMPUTE_ONE(1, 4 * wv + 1);
        __builtin_amdgcn_sched_barrier(0);
        // pair 1
        #pragma unroll
        for (int k = 0; k < 3; ++k) {
            const int t = k * 64 + ln;
            const int ch = t / 96, rem = t - ch * 96, row = rem >> 4, q = rem & 15;
            *(f4_t*)&lds[wv][ch][row][4 * q] = rb[k];
        }
        WAVE_FENCE();
        COMPUTE_ONE(0, 4 * wv + 2);
        COMPUTE_ONE(1, 4 * wv + 3);
    } else {
        // seam-straddling x-window (2 of 6 x-tiles): per-element gather
        float sa[12], sb[12];
        const int tcol = stage_b + ln;
        const int cmem = (tcol >= 512) ? tcol - 512 : tcol + 512;
        #pragma unroll
        for (int s = 0; s < 12; ++s) {
            const int ch = s / 6, row = s - ch * 6;
            const int rr = byb + row;
            const int rmem = (rr >= 512) ? rr - 512 : rr + 512;
            sa[s] = re[(size_t)(4 * wv + ch) * (N_IN_ * N_IN_) + (size_t)rmem * N_IN_ + cmem];
        }
        #pragma unroll
        for (int s = 0; s < 12; ++s) {
            const int ch = s / 6, row = s - ch * 6;
            const int rr = byb + row;
            const int rmem = (rr >= 512) ? rr - 512 : rr + 512;
            sb[s] = re[(size_t)(4 * wv + 2 + ch) * (N_IN_ * N_IN_) + (size_t)rmem * N_IN_ + cmem];
        }
        SETUP_W();
        __builtin_amdgcn_sched_barrier(0);
        #pragma unroll
        for (int s = 0; s < 12; ++s) {
            const int ch = s / 6, row = s - ch * 6;
            lds[wv][ch][row][ln] = sa[s];
        }
        WAVE_FENCE();
        COMPUTE_ONE(0, 4 * wv + 0);
        COMPUTE_ONE(1, 4 * wv + 1);
        __builtin_amdgcn_sched_barrier(0);
        #pragma unroll
        for (int s = 0; s < 12; ++s) {
            const int ch = s / 6, row = s - ch * 6;
            lds[wv][ch][row][ln] = sb[s];
        }
        WAVE_FENCE();
        COMPUTE_ONE(0, 4 * wv + 2);
        COMPUTE_ONE(1, 4 * wv + 3);
    }
}

// ---------------- Defensive: complex-interleaved output variant --------------
__global__ __launch_bounds__(256)
void resample_cplx(const float* __restrict__ re,
                   const float* __restrict__ im,
                   float2* __restrict__ out) {
    const int x = blockIdx.x * 256 + threadIdx.x;
    const int y = blockIdx.y;
    const int jx = x < 768 ? x + 768 : x - 768;
    const int jy = y < 768 ? y + 768 : y - 768;

    float ux = u_of_j(jx), uy = u_of_j(jy);
    int bx = min(max((int)floorf(ux) - 1, 0), N_IN_ - 4);
    int by = min(max((int)floorf(uy) - 1, 0), N_IN_ - 4);
    float wx[4], wy[4];
    #pragma unroll
    for (int d = 0; d < 4; ++d) {
        wx[d] = cubic_w(ux - (float)(bx + d));
        wy[d] = 3.0f * cubic_w(uy - (float)(by + d));
    }
    float w[4][4];
    #pragma unroll
    for (int dy = 0; dy < 4; ++dy)
        #pragma unroll
        for (int dx = 0; dx < 4; ++dx) w[dy][dx] = wy[dy] * wx[dx];

    int rofs[4];
    #pragma unroll
    for (int dy = 0; dy < 4; ++dy) {
        int t = by + dy;
        rofs[dy] = ((t >= 512) ? (t - 512) : (t + 512)) * N_IN_;
    }
    int cm[4];
    #pragma unroll
    for (int d = 0; d < 4; ++d) {
        int t = bx + d;
        cm[d] = (t >= 512) ? (t - 512) : (t + 512);
    }

    const int outbase = y * N_OUT_ + x;
    for (int c = 0; c < N_CH; ++c) {
        const float* rec = re + (size_t)c * (N_IN_ * N_IN_);
        const float* imc = im + (size_t)c * (N_IN_ * N_IN_);
        float ar = 0.0f, ai = 0.0f;
        #pragma unroll
        for (int dy = 0; dy < 4; ++dy) {
            #pragma unroll
            for (int d = 0; d < 4; ++d) {
                ar = fmaf(w[dy][d], rec[rofs[dy] + cm[d]], ar);
                ai = fmaf(w[dy][d], imc[rofs[dy] + cm[d]], ai);
            }
        }
        out[(size_t)c * (N_OUT_ * N_OUT_) + outbase] = make_float2(ar, ai);
    }
}

extern "C" void kernel_launch(void* const* d_in, const int* in_sizes, int n_in,
                              void* d_out, int out_size, void* d_ws, size_t ws_size,
                              hipStream_t stream) {
    const float* re = (const float*)d_in[0];   // kimage_real (16,1024,1024)
    const float* im = (const float*)d_in[1];   // kimage_imag (16,1024,1024)

    if (out_size >= 2 * N_CH * N_OUT_ * N_OUT_) {
        // complex-interleaved output (defensive; not the observed case)
        resample_cplx<<<dim3(N_OUT_ / 256, N_OUT_), dim3(256), 0, stream>>>(
            re, im, (float2*)d_out);
    } else {
        fused_pipe<<<dim3(N_OUT_ / XT, N_OUT_ / TY), dim3(256), 0, stream>>>(
            re, (float*)d_out);
    }
}

// Round 12
// 36.734 us; speedup vs baseline: 1.1256x; 1.0079x over previous
//
#include <hip/hip_runtime.h>

#define N_IN_   1024
#define N_OUT_  1536
#define N_CH    16
#define TY      6       // output rows per block tile (6 | 768)
#define XT      256     // output cols per block tile
#define XW      64      // staged input x-window (max span 61 < 64)

typedef float f4_t __attribute__((ext_vector_type(4)));

// Catmull-Rom-style cubic kernel, matching the reference formula in f32.
// Exact 0 for |x| >= 2 -> widened tap windows are formula-identical.
__device__ __forceinline__ float cubic_w(float x) {
    float ax = fabsf(x);
    float f1 = 1.0f + ax * ax * (1.5f * ax - 2.5f);
    float t  = 2.0f - ax;
    float f2 = -0.5f * (ax - 1.0f) * t * t;
    return ax <= 1.0f ? f1 : (ax < 2.0f ? f2 : 0.0f);
}

__device__ __forceinline__ float u_of_j(int j) {
    const float c0 = -0.5f / 0.05f;                        // k_in[0] = -10
    const float c1 = (-0.5f + 1.0f / 1023.0f) / 0.05f;     // k_in[1]
    const float h  = c1 - c0;
    float kout = (-0.5f + (float)j * (1.0f / 1535.0f)) / 0.15f;
    return (kout - c0) / h;                                // in [341, 682]
}

// One block: output tile [y0..y0+5] x [X0..X0+255] x all 16 channels.
// Wave w owns channels 4w..4w+3 end-to-end -> no block barrier. Two
// channel-pairs, software-pipelined with STAGGERED issue: pair1's global
// loads are issued only after pair0's ds_writes (sched_barrier-pinned), so
// the chip-wide t=0 read burst is halved and pair1's fetch overlaps pair0's
// compute + store drain.
__global__ __launch_bounds__(256)
void fused_pipe(const float* __restrict__ re, float* __restrict__ out) {
    const int tid = threadIdx.x;
    const int wv  = tid >> 6;       // wave 0..3
    const int ln  = tid & 63;       // lane
    const int X0  = blockIdx.x * XT;
    const int y0  = blockIdx.y * TY;
    const int jx0 = X0 < 768 ? X0 + 768 : X0 - 768;   // contiguous over tile
    const int jy0 = y0 < 768 ? y0 + 768 : y0 - 768;

    int stage_b = (int)floorf(u_of_j(jx0)) - 1;
    stage_b = min(max(stage_b, 0), N_IN_ - XW);
    int byb = (int)floorf(u_of_j(jy0)) - 1;
    byb = min(max(byb, 0), N_IN_ - TY);

    __shared__ __align__(16) float lds[4][2][TY][XW];   // [wave][ch-in-pair][row][col] 12 KB
    __shared__ __align__(16) float wlds[4][TY][8];      // per-wave y-weight matrix copy

    const bool hi = (stage_b >= 512);
    const bool lo = (stage_b + XW <= 512);
    const bool contig = hi || lo;                       // block-uniform branch
    const int xbase = hi ? (stage_b - 512) : (stage_b + 512);

    // per-thread x weights (computed under stage-load latency)
    const int col0 = 4 * ln;
    const int jxc  = jx0 + col0;
    int w0;
    float wx6[4][6];

// wmat (wave-local copy in LDS; RES_RATIO=3 folded) + wx6 setup
#define SETUP_W() do {                                                        \
    if (ln < 36) {                                                            \
        const int j_ = ln / 6, i_ = ln - 6 * j_;                              \
        wlds[wv][j_][i_] = 3.0f * cubic_w(u_of_j(jy0 + i_) - (float)(byb + j_)); \
    }                                                                         \
    w0 = (int)floorf(u_of_j(jxc)) - 1 - stage_b;                              \
    w0 = min(max(w0, 0), XW - 6);                                             \
    _Pragma("unroll")                                                         \
    for (int k = 0; k < 4; ++k) {                                             \
        float uk = u_of_j(jxc + k);                                           \
        _Pragma("unroll")                                                     \
        for (int j = 0; j < 6; ++j)                                           \
            wx6[k][j] = cubic_w(uk - (float)(stage_b + w0 + j));              \
    }                                                                         \
} while (0)

// compute + store one channel from lds[wv][PL] (PL static)
#define COMPUTE_ONE(PL, CCH) do {                                             \
    float acc[TY][4];                                                         \
    _Pragma("unroll")                                                         \
    for (int i = 0; i < TY; ++i) {                                            \
        acc[i][0] = 0.f; acc[i][1] = 0.f; acc[i][2] = 0.f; acc[i][3] = 0.f;   \
    }                                                                         \
    _Pragma("unroll")                                                         \
    for (int j = 0; j < TY; ++j) {                                            \
        const float* p = &lds[wv][PL][j][w0];                                 \
        const float L0 = p[0], L1 = p[1], L2 = p[2],                          \
                    L3 = p[3], L4 = p[4], L5 = p[5];                          \
        float xr0, xr1, xr2, xr3;                                             \
        xr0 = fmaf(wx6[0][5], L5, fmaf(wx6[0][4], L4, fmaf(wx6[0][3], L3,     \
              fmaf(wx6[0][2], L2, fmaf(wx6[0][1], L1, wx6[0][0] * L0)))));    \
        xr1 = fmaf(wx6[1][5], L5, fmaf(wx6[1][4], L4, fmaf(wx6[1][3], L3,     \
              fmaf(wx6[1][2], L2, fmaf(wx6[1][1], L1, wx6[1][0] * L0)))));    \
        xr2 = fmaf(wx6[2][5], L5, fmaf(wx6[2][4], L4, fmaf(wx6[2][3], L3,     \
              fmaf(wx6[2][2], L2, fmaf(wx6[2][1], L1, wx6[2][0] * L0)))));    \
        xr3 = fmaf(wx6[3][5], L5, fmaf(wx6[3][4], L4, fmaf(wx6[3][3], L3,     \
              fmaf(wx6[3][2], L2, fmaf(wx6[3][1], L1, wx6[3][0] * L0)))));    \
        const f4_t wlo = *(const f4_t*)&wlds[wv][j][0];                       \
        const float w4 = wlds[wv][j][4], w5 = wlds[wv][j][5];                 \
        acc[0][0] = fmaf(wlo.x, xr0, acc[0][0]);                              \
        acc[0][1] = fmaf(wlo.x, xr1, acc[0][1]);                              \
        acc[0][2] = fmaf(wlo.x, xr2, acc[0][2]);                              \
        acc[0][3] = fmaf(wlo.x, xr3, acc[0][3]);                              \
        acc[1][0] = fmaf(wlo.y, xr0, acc[1][0]);                              \
        acc[1][1] = fmaf(wlo.y, xr1, acc[1][1]);                              \
        acc[1][2] = fmaf(wlo.y, xr2, acc[1][2]);                              \
        acc[1][3] = fmaf(wlo.y, xr3, acc[1][3]);                              \
        acc[2][0] = fmaf(wlo.z, xr0, acc[2][0]);                              \
        acc[2][1] = fmaf(wlo.z, xr1, acc[2][1]);                              \
        acc[2][2] = fmaf(wlo.z, xr2, acc[2][2]);                              \
        acc[2][3] = fmaf(wlo.z, xr3, acc[2][3]);                              \
        acc[3][0] = fmaf(wlo.w, xr0, acc[3][0]);                              \
        acc[3][1] = fmaf(wlo.w, xr1, acc[3][1]);                              \
        acc[3][2] = fmaf(wlo.w, xr2, acc[3][2]);                              \
        acc[3][3] = fmaf(wlo.w, xr3, acc[3][3]);                              \
        acc[4][0] = fmaf(w4, xr0, acc[4][0]);                                 \
        acc[4][1] = fmaf(w4, xr1, acc[4][1]);                                 \
        acc[4][2] = fmaf(w4, xr2, acc[4][2]);                                 \
        acc[4][3] = fmaf(w4, xr3, acc[4][3]);                                 \
        acc[5][0] = fmaf(w5, xr0, acc[5][0]);                                 \
        acc[5][1] = fmaf(w5, xr1, acc[5][1]);                                 \
        acc[5][2] = fmaf(w5, xr2, acc[5][2]);                                 \
        acc[5][3] = fmaf(w5, xr3, acc[5][3]);                                 \
    }                                                                         \
    float* ob = out + (size_t)(CCH) * (N_OUT_ * N_OUT_)                       \
                    + (size_t)y0 * N_OUT_ + X0 + col0;                        \
    _Pragma("unroll")                                                         \
    for (int i = 0; i < TY; ++i) {                                            \
        f4_t a = { acc[i][0], acc[i][1], acc[i][2], acc[i][3] };              \
        __builtin_nontemporal_store(a, (f4_t*)(ob + (size_t)i * N_OUT_));     \
    }                                                                         \
} while (0)

#define WAVE_FENCE() do {                                                     \
    asm volatile("s_waitcnt lgkmcnt(0)" ::: "memory");                        \
    __builtin_amdgcn_sched_barrier(0);                                        \
} while (0)

    if (contig) {
        // f4 task decode: t=k*64+ln; ch=t/96; row=(t-96ch)>>4; q=t&15
        f4_t ra[3], rb[3];
        #pragma unroll
        for (int k = 0; k < 3; ++k) {
            const int t = k * 64 + ln;
            const int ch = t / 96, rem = t - ch * 96, row = rem >> 4, q = rem & 15;
            const int rr = byb + row;
            const int rmem = (rr >= 512) ? rr - 512 : rr + 512;
            __builtin_memcpy(&ra[k], re + (size_t)(4 * wv + ch) * (N_IN_ * N_IN_)
                                        + (size_t)rmem * N_IN_ + xbase + 4 * q, 16);
        }
        SETUP_W();
        __builtin_amdgcn_sched_barrier(0);
        // pair 0 ds_write: compiler emits counted vmcnt for ra only
        #pragma unroll
        for (int k = 0; k < 3; ++k) {
            const int t = k * 64 + ln;
            const int ch = t / 96, rem = t - ch * 96, row = rem >> 4, q = rem & 15;
            *(f4_t*)&lds[wv][ch][row][4 * q] = ra[k];
        }
        __builtin_amdgcn_sched_barrier(0);
        // STAGGERED: pair 1 loads issue only now -> overlap pair0 compute+stores
        #pragma unroll
        for (int k = 0; k < 3; ++k) {
            const int t = k * 64 + ln;
            const int ch = t / 96, rem = t - ch * 96, row = rem >> 4, q = rem & 15;
            const int rr = byb + row;
            const int rmem = (rr >= 512) ? rr - 512 : rr + 512;
            __builtin_memcpy(&rb[k], re + (size_t)(4 * wv + 2 + ch) * (N_IN_ * N_IN_)
                                        + (size_t)rmem * N_IN_ + xbase + 4 * q, 16);
        }
        __builtin_amdgcn_sched_barrier(0);
        WAVE_FENCE();
        COMPUTE_ONE(0, 4 * wv + 0);
        COMPUTE_ONE(1, 4 * wv + 1);
        __builtin_amdgcn_sched_barrier(0);
        // pair 1 ds_write (vmcnt waits rb)
        #pragma unroll
        for (int k = 0; k < 3; ++k) {
            const int t = k * 64 + ln;
            const int ch = t / 96, rem = t - ch * 96, row = rem >> 4, q = rem & 15;
            *(f4_t*)&lds[wv][ch][row][4 * q] = rb[k];
        }
        WAVE_FENCE();
        COMPUTE_ONE(0, 4 * wv + 2);
        COMPUTE_ONE(1, 4 * wv + 3);
    } else {
        // seam-straddling x-window (2 of 6 x-tiles): per-element gather
        float sa[12], sb[12];
        const int tcol = stage_b + ln;
        const int cmem = (tcol >= 512) ? tcol - 512 : tcol + 512;
        #pragma unroll
        for (int s = 0; s < 12; ++s) {
            const int ch = s / 6, row = s - ch * 6;
            const int rr = byb + row;
            const int rmem = (rr >= 512) ? rr - 512 : rr + 512;
            sa[s] = re[(size_t)(4 * wv + ch) * (N_IN_ * N_IN_) + (size_t)rmem * N_IN_ + cmem];
        }
        SETUP_W();
        __builtin_amdgcn_sched_barrier(0);
        #pragma unroll
        for (int s = 0; s < 12; ++s) {
            const int ch = s / 6, row = s - ch * 6;
            lds[wv][ch][row][ln] = sa[s];
        }
        __builtin_amdgcn_sched_barrier(0);
        #pragma unroll
        for (int s = 0; s < 12; ++s) {
            const int ch = s / 6, row = s - ch * 6;
            const int rr = byb + row;
            const int rmem = (rr >= 512) ? rr - 512 : rr + 512;
            sb[s] = re[(size_t)(4 * wv + 2 + ch) * (N_IN_ * N_IN_) + (size_t)rmem * N_IN_ + cmem];
        }
        __builtin_amdgcn_sched_barrier(0);
        WAVE_FENCE();
        COMPUTE_ONE(0, 4 * wv + 0);
        COMPUTE_ONE(1, 4 * wv + 1);
        __builtin_amdgcn_sched_barrier(0);
        #pragma unroll
        for (int s = 0; s < 12; ++s) {
            const int ch = s / 6, row = s - ch * 6;
            lds[wv][ch][row][ln] = sb[s];
        }
        WAVE_FENCE();
        COMPUTE_ONE(0, 4 * wv + 2);
        COMPUTE_ONE(1, 4 * wv + 3);
    }
}

// ---------------- Defensive: complex-interleaved output variant --------------
__global__ __launch_bounds__(256)
void resample_cplx(const float* __restrict__ re,
                   const float* __restrict__ im,
                   float2* __restrict__ out) {
    const int x = blockIdx.x * 256 + threadIdx.x;
    const int y = blockIdx.y;
    const int jx = x < 768 ? x + 768 : x - 768;
    const int jy = y < 768 ? y + 768 : y - 768;

    float ux = u_of_j(jx), uy = u_of_j(jy);
    int bx = min(max((int)floorf(ux) - 1, 0), N_IN_ - 4);
    int by = min(max((int)floorf(uy) - 1, 0), N_IN_ - 4);
    float wx[4], wy[4];
    #pragma unroll
    for (int d = 0; d < 4; ++d) {
        wx[d] = cubic_w(ux - (float)(bx + d));
        wy[d] = 3.0f * cubic_w(uy - (float)(by + d));
    }
    float w[4][4];
    #pragma unroll
    for (int dy = 0; dy < 4; ++dy)
        #pragma unroll
        for (int dx = 0; dx < 4; ++dx) w[dy][dx] = wy[dy] * wx[dx];

    int rofs[4];
    #pragma unroll
    for (int dy = 0; dy < 4; ++dy) {
        int t = by + dy;
        rofs[dy] = ((t >= 512) ? (t - 512) : (t + 512)) * N_IN_;
    }
    int cm[4];
    #pragma unroll
    for (int d = 0; d < 4; ++d) {
        int t = bx + d;
        cm[d] = (t >= 512) ? (t - 512) : (t + 512);
    }

    const int outbase = y * N_OUT_ + x;
    for (int c = 0; c < N_CH; ++c) {
        const float* rec = re + (size_t)c * (N_IN_ * N_IN_);
        const float* imc = im + (size_t)c * (N_IN_ * N_IN_);
        float ar = 0.0f, ai = 0.0f;
        #pragma unroll
        for (int dy = 0; dy < 4; ++dy) {
            #pragma unroll
            for (int d = 0; d < 4; ++d) {
                ar = fmaf(w[dy][d], rec[rofs[dy] + cm[d]], ar);
                ai = fmaf(w[dy][d], imc[rofs[dy] + cm[d]], ai);
            }
        }
        out[(size_t)c * (N_OUT_ * N_OUT_) + outbase] = make_float2(ar, ai);
    }
}

extern "C" void kernel_launch(void* const* d_in, const int* in_sizes, int n_in,
                              void* d_out, int out_size, void* d_ws, size_t ws_size,
                              hipStream_t stream) {
    const float* re = (const float*)d_in[0];   // kimage_real (16,1024,1024)
    const float* im = (const float*)d_in[1];   // kimage_imag (16,1024,1024)

    if (out_size >= 2 * N_CH * N_OUT_ * N_OUT_) {
        // complex-interleaved output (defensive; not the observed case)
        resample_cplx<<<dim3(N_OUT_ / 256, N_OUT_), dim3(256), 0, stream>>>(
            re, im, (float2*)d_out);
    } else {
        fused_pipe<<<dim3(N_OUT_ / XT, N_OUT_ / TY), dim3(256), 0, stream>>>(
            re, (float*)d_out);
    }
}